// Round 1
// 15532.066 us; speedup vs baseline: 1.1877x; 1.1877x over previous
//
#include <hip/hip_runtime.h>
#include <hip/hip_bf16.h>
#include <math.h>

#define D 512
#define HID 2048
#define LAYERS 4
#define V 32000
#define BATCH 2
#define T 1025
#define MB 128
#define NH 8
#define DH 64
#define NTOK 256            // BATCH*MB rows per chunk
#define LR 0.0003f
#define NCHUNK 8
#define SPLITK 20
#define SKLEN 1600          // 32000 / 20, multiple of 64

typedef unsigned short u16;
typedef __attribute__((ext_vector_type(8))) short bf16x8;
typedef __attribute__((ext_vector_type(4))) float f32x4;
typedef __attribute__((ext_vector_type(4))) unsigned short u16x4;

// ---- fp32 <-> bf16 (RNE) ----
__device__ __forceinline__ u16 f2b(float f) {
    unsigned int x = __float_as_uint(f);
    unsigned int r = (x + 0x7FFFu + ((x >> 16) & 1u)) >> 16;
    return (u16)r;
}
__device__ __forceinline__ float b2f(u16 u) {
    return __uint_as_float(((unsigned int)u) << 16);
}

// ---- async global->LDS 16B ----
__device__ __forceinline__ void gload16(const u16* g, u16* l) {
    __builtin_amdgcn_global_load_lds(
        (const __attribute__((address_space(1))) unsigned int*)g,
        (__attribute__((address_space(3))) unsigned int*)l, 16, 0, 0);
}

// =================== MFMA GEMM core ===================
// C[M][N] = A[M][K] * Bt[N][K]^T ; A,Bt bf16 K-contiguous. 64x64 tile, BK=64.
__device__ __forceinline__ void gemm_core(
    const u16* __restrict__ A, int lda, const u16* __restrict__ Bt, int ldb,
    int kBegin, int kEnd, int m0, int n0, u16* As, u16* Bs, f32x4 acc[2][2])
{
    int t = threadIdx.x, w = t >> 6, l = t & 63;
    int srow = w * 8 + (l >> 3);     // staging row 0..31 (+32 second half)
    int qs = l & 7;                  // LDS quad slot
    int gq = qs ^ (srow & 7);        // swizzled global quad
    const u16* Ag = A + (size_t)(m0 + srow) * lda + gq * 8;
    const u16* Bg = Bt + (size_t)(n0 + srow) * ldb + gq * 8;
    u16* AsP = As + srow * 64 + qs * 8;
    u16* BsP = Bs + srow * 64 + qs * 8;
    size_t a32 = (size_t)32 * lda, b32 = (size_t)32 * ldb;
    int fr = l & 15, fq = l >> 4;
    int wr = (w >> 1) * 32, wc = (w & 1) * 32;  // wave sub-tile
    const u16* arp = As + (size_t)(wr + fr) * 64;
    const u16* brp = Bs + (size_t)(wc + fr) * 64;
    int sw = fr & 7;
    for (int k0 = kBegin; k0 < kEnd; k0 += 64) {
        if (k0 != kBegin) __syncthreads();
        gload16(Ag + k0, AsP);
        gload16(Ag + a32 + k0, AsP + 32 * 64);
        gload16(Bg + k0, BsP);
        gload16(Bg + b32 + k0, BsP + 32 * 64);
        __syncthreads();
#pragma unroll
        for (int kk = 0; kk < 2; kk++) {
            int sq = ((kk * 4 + fq) ^ sw) * 8;
            bf16x8 a0 = *(const bf16x8*)(arp + sq);
            bf16x8 a1 = *(const bf16x8*)(arp + 16 * 64 + sq);
            bf16x8 b0 = *(const bf16x8*)(brp + sq);
            bf16x8 b1 = *(const bf16x8*)(brp + 16 * 64 + sq);
            acc[0][0] = __builtin_amdgcn_mfma_f32_16x16x32_bf16(a0, b0, acc[0][0], 0, 0, 0);
            acc[0][1] = __builtin_amdgcn_mfma_f32_16x16x32_bf16(a0, b1, acc[0][1], 0, 0, 0);
            acc[1][0] = __builtin_amdgcn_mfma_f32_16x16x32_bf16(a1, b0, acc[1][0], 0, 0, 0);
            acc[1][1] = __builtin_amdgcn_mfma_f32_16x16x32_bf16(a1, b1, acc[1][1], 0, 0, 0);
        }
    }
}

// generic GEMM: optional bias, residual, chunk-row-remap, split-K partials
__global__ __launch_bounds__(256) void gemm64(
    const u16* __restrict__ A, int lda, const u16* __restrict__ Bt, int ldb,
    float* __restrict__ C, int ldc, int kLen, int zStride,
    const float* __restrict__ bias, const float* __restrict__ res, int ldres, int remapc)
{
    __shared__ __align__(16) u16 S[8192];
    u16* As = S; u16* Bs = S + 4096;
    f32x4 zero = {0.f, 0.f, 0.f, 0.f};
    f32x4 acc[2][2] = {{zero, zero}, {zero, zero}};
    int z = blockIdx.z;
    int m0 = blockIdx.y * 64, n0 = blockIdx.x * 64;
    gemm_core(A, lda, Bt, ldb, z * kLen, z * kLen + kLen, m0, n0, As, Bs, acc);
    float* Cz = C + (size_t)z * zStride;
    int l = threadIdx.x & 63, w = threadIdx.x >> 6;
    int wr = (w >> 1) * 32, wc = (w & 1) * 32;
    int cn = n0 + wc + (l & 15);
    int rb = wr + (l >> 4) * 4;
#pragma unroll
    for (int i = 0; i < 2; i++)
#pragma unroll
        for (int r = 0; r < 4; r++) {
            int m = m0 + rb + i * 16 + r;
            int mo = (remapc >= 0) ? ((m >> 7) * 1024 + remapc * 128 + (m & 127)) : m;
#pragma unroll
            for (int j = 0; j < 2; j++) {
                int n = cn + j * 16;
                float v = acc[i][j][r];
                if (bias) v += bias[n];
                if (res) v += res[(size_t)m * ldres + n];
                Cz[(size_t)mo * ldc + n] = v;
            }
        }
}

// FF1 GEMM + bias + gelu fused: writes pre-act fp32 (gbuf), act bf16 (u) and act^T (uT)
__global__ __launch_bounds__(256) void gemm64_gelu(
    const u16* __restrict__ A, int lda, const u16* __restrict__ Bt, int ldb, int K,
    const float* __restrict__ bias, float* __restrict__ gout,
    u16* __restrict__ u, u16* __restrict__ uT)
{
    __shared__ __align__(16) u16 S[8192];
    u16* As = S; u16* Bs = S + 4096;
    f32x4 zero = {0.f, 0.f, 0.f, 0.f};
    f32x4 acc[2][2] = {{zero, zero}, {zero, zero}};
    int m0 = blockIdx.y * 64, n0 = blockIdx.x * 64;
    gemm_core(A, lda, Bt, ldb, 0, K, m0, n0, As, Bs, acc);
    int t = threadIdx.x, l = t & 63, w = t >> 6;
    int wr = (w >> 1) * 32, wc = (w & 1) * 32;
    int cnl = wc + (l & 15);
    int rbl = wr + (l >> 4) * 4;
    __syncthreads();           // done reading staging LDS
    u16* Ts = S;               // [64 n][72] bf16 tile for transposed store
#pragma unroll
    for (int i = 0; i < 2; i++)
#pragma unroll
        for (int r = 0; r < 4; r++) {
            int ml = rbl + i * 16 + r;
            size_t grow = (size_t)(m0 + ml) * HID;
#pragma unroll
            for (int j = 0; j < 2; j++) {
                int nl = cnl + j * 16;
                float v = acc[i][j][r] + bias[n0 + nl];
                gout[grow + n0 + nl] = v;
                float th = tanhf(0.7978845608028654f * (v + 0.044715f * v * v * v));
                u16 bb = f2b(0.5f * v * (1.f + th));
                u[grow + n0 + nl] = bb;
                Ts[nl * 72 + ml] = bb;
            }
        }
    __syncthreads();
    int cc = t >> 2, rs = (t & 3) * 16;
    u16* opT = uT + (size_t)(n0 + cc) * NTOK + m0 + rs;
#pragma unroll
    for (int k2 = 0; k2 < 16; k2++) opT[k2] = Ts[cc * 72 + rs + k2];
}

// du GEMM + gelu-bwd fused: dg = (dh @ W2^T) * gelu'(g); writes dg bf16 + dg^T
__global__ __launch_bounds__(256) void gemm64_dgelu(
    const u16* __restrict__ A, int lda, const u16* __restrict__ Bt, int ldb, int K,
    const float* __restrict__ g, u16* __restrict__ dg, u16* __restrict__ dgT)
{
    __shared__ __align__(16) u16 S[8192];
    u16* As = S; u16* Bs = S + 4096;
    f32x4 zero = {0.f, 0.f, 0.f, 0.f};
    f32x4 acc[2][2] = {{zero, zero}, {zero, zero}};
    int m0 = blockIdx.y * 64, n0 = blockIdx.x * 64;
    gemm_core(A, lda, Bt, ldb, 0, K, m0, n0, As, Bs, acc);
    int t = threadIdx.x, l = t & 63, w = t >> 6;
    int wr = (w >> 1) * 32, wc = (w & 1) * 32;
    int cnl = wc + (l & 15);
    int rbl = wr + (l >> 4) * 4;
    __syncthreads();
    u16* Ts = S;
#pragma unroll
    for (int i = 0; i < 2; i++)
#pragma unroll
        for (int r = 0; r < 4; r++) {
            int ml = rbl + i * 16 + r;
            size_t grow = (size_t)(m0 + ml) * HID;
#pragma unroll
            for (int j = 0; j < 2; j++) {
                int nl = cnl + j * 16;
                float x = g[grow + n0 + nl];
                const float cc_ = 0.7978845608028654f, a = 0.044715f;
                float th = tanhf(cc_ * (x + a * x * x * x));
                float dt = (1.f - th * th) * cc_ * (1.f + 3.f * a * x * x);
                float grad = 0.5f * (1.f + th) + 0.5f * x * dt;
                u16 bb = f2b(acc[i][j][r] * grad);
                dg[grow + n0 + nl] = bb;
                Ts[nl * 72 + ml] = bb;
            }
        }
    __syncthreads();
    int cc = t >> 2, rs = (t & 3) * 16;
    u16* opT = dgT + (size_t)(n0 + cc) * NTOK + m0 + rs;
#pragma unroll
    for (int k2 = 0; k2 < 16; k2++) opT[k2] = Ts[cc * 72 + rs + k2];
}

// TN weight-update GEMM: P -= lr*acc; refresh bf16 natural + (coalesced) transposed
// copies; blocks with m0==0 also fold in the bias update (colsum of Bt over K).
__global__ __launch_bounds__(256) void gemm64_upd(
    const u16* __restrict__ A, int lda, const u16* __restrict__ Bt, int ldb,
    float* __restrict__ P, int ldp, int K, float lr,
    u16* __restrict__ Wn, u16* __restrict__ Wt, int ldt, float* __restrict__ bias)
{
    __shared__ __align__(16) u16 S[8192];
    u16* As = S; u16* Bs = S + 4096;
    f32x4 zero = {0.f, 0.f, 0.f, 0.f};
    f32x4 acc[2][2] = {{zero, zero}, {zero, zero}};
    int m0 = blockIdx.y * 64, n0 = blockIdx.x * 64;
    gemm_core(A, lda, Bt, ldb, 0, K, m0, n0, As, Bs, acc);
    int t = threadIdx.x, l = t & 63, w = t >> 6;
    int wr = (w >> 1) * 32, wc = (w & 1) * 32;
    int cnl = wc + (l & 15);
    int rbl = wr + (l >> 4) * 4;
    __syncthreads();
    u16* Ts = S;
#pragma unroll
    for (int i = 0; i < 2; i++)
#pragma unroll
        for (int r = 0; r < 4; r++) {
            int ml = rbl + i * 16 + r;
            int m = m0 + ml;
#pragma unroll
            for (int j = 0; j < 2; j++) {
                int nl = cnl + j * 16;
                int n = n0 + nl;
                size_t ip = (size_t)m * ldp + n;
                float nv = P[ip] - lr * acc[i][j][r];
                P[ip] = nv;
                u16 bb = f2b(nv);
                Wn[ip] = bb;
                Ts[nl * 72 + ml] = bb;
            }
        }
    __syncthreads();
    int cc = t >> 2, rs = (t & 3) * 16;
    u16* opT = Wt + (size_t)(n0 + cc) * ldt + m0 + rs;
#pragma unroll
    for (int k2 = 0; k2 < 16; k2++) opT[k2] = Ts[cc * 72 + rs + k2];
    // fused bias update: bias[n] -= lr * sum_k Bt[n][k]   (K == NTOK == 256)
    if (bias && m0 == 0) {
        int nl = t >> 2, ks = (t & 3) * 64;
        const u16* bp = Bt + (size_t)(n0 + nl) * ldb + ks;
        float s = 0.f;
#pragma unroll
        for (int k = 0; k < 64; k += 8) {
            bf16x8 v8 = *(const bf16x8*)(bp + k);
#pragma unroll
            for (int e = 0; e < 8; e++) s += b2f((u16)v8[e]);
        }
        s += __shfl_xor(s, 1, 64);
        s += __shfl_xor(s, 2, 64);
        if ((t & 3) == 0) bias[n0 + nl] -= lr * s;
    }
}

// ---- fp32 [R][C] -> bf16 natural [R][C] + bf16 transposed [C][R], 64x64 tiles ----
__global__ __launch_bounds__(256) void conv_nt(const float* __restrict__ in,
        u16* __restrict__ outN, u16* __restrict__ outT, int R, int C) {
    __shared__ u16 Ts[64][72];
    int c0 = blockIdx.x * 64, r0 = blockIdx.y * 64;
    int t = threadIdx.x, lr = t >> 2, cs = (t & 3) * 16;
    const float* ip = in + (size_t)(r0 + lr) * C + c0 + cs;
    u16* op = outN + (size_t)(r0 + lr) * C + c0 + cs;
#pragma unroll
    for (int k = 0; k < 16; k++) {
        u16 bb = f2b(ip[k]);
        op[k] = bb;
        Ts[lr][cs + k] = bb;
    }
    __syncthreads();
    int cc = t >> 2, rs = (t & 3) * 16;
    u16* opT = outT + (size_t)(c0 + cc) * R + r0 + rs;
#pragma unroll
    for (int k = 0; k < 16; k++) opT[k] = Ts[rs + k][cc];
}

// ---------------- reductions ----------------
__device__ __forceinline__ float block_sum(float v, float* sbuf) {
    int t = threadIdx.x;
    for (int o = 32; o > 0; o >>= 1) v += __shfl_down(v, o, 64);
    if ((t & 63) == 0) sbuf[t >> 6] = v;
    __syncthreads();
    int nw = blockDim.x >> 6;
    float r = (t < nw) ? sbuf[t] : 0.f;
    if (t < 64) { for (int o = 32; o > 0; o >>= 1) r += __shfl_down(r, o, 64); }
    if (t == 0) sbuf[0] = r;
    __syncthreads();
    float out = sbuf[0];
    __syncthreads();
    return out;
}
__device__ __forceinline__ float block_max(float v, float* sbuf) {
    int t = threadIdx.x;
    for (int o = 32; o > 0; o >>= 1) v = fmaxf(v, __shfl_down(v, o, 64));
    if ((t & 63) == 0) sbuf[t >> 6] = v;
    __syncthreads();
    int nw = blockDim.x >> 6;
    float r = (t < nw) ? sbuf[t] : -1e30f;
    if (t < 64) { for (int o = 32; o > 0; o >>= 1) r = fmaxf(r, __shfl_down(r, o, 64)); }
    if (t == 0) sbuf[0] = r;
    __syncthreads();
    float out = sbuf[0];
    __syncthreads();
    return out;
}

// ---------------- embedding + layer-0 ln1 fused ----------------
__global__ void embed_ln(const int* __restrict__ x, const float* __restrict__ emb,
                         const float* __restrict__ pos, const float* __restrict__ s,
                         const float* __restrict__ bb, float* __restrict__ h0,
                         u16* __restrict__ y, int c) {
    __shared__ float sbuf[8];
    __shared__ float xs[D];
    int n = blockIdx.x, b = n >> 7, i = n & 127;
    int tok = x[b * T + c * MB + i];
    float sum = 0.f;
    for (int d = threadIdx.x; d < D; d += blockDim.x) {
        float v = emb[(size_t)tok * D + d] + pos[(size_t)i * D + d];
        xs[d] = v;
        h0[(size_t)n * D + d] = v;
        sum += v;
    }
    __syncthreads();
    float mean = block_sum(sum, sbuf) / D;
    float vs = 0.f;
    for (int d = threadIdx.x; d < D; d += blockDim.x) { float t = xs[d] - mean; vs += t * t; }
    float var = block_sum(vs, sbuf) / D;
    float rstd = rsqrtf(var + 1e-5f);
    for (int d = threadIdx.x; d < D; d += blockDim.x)
        y[(size_t)n * D + d] = f2b((xs[d] - mean) * rstd * s[d] + bb[d]);
}

// ---------------- layernorm fwd (row cached in LDS) ----------------
__global__ void ln_fwd(const float* __restrict__ x, const float* __restrict__ s,
                       const float* __restrict__ bb, u16* __restrict__ y,
                       u16* __restrict__ yT) {
    __shared__ float sbuf[8];
    __shared__ float xs[D];
    int row = blockIdx.x;
    const float* xr = x + (size_t)row * D;
    float sum = 0;
    for (int d = threadIdx.x; d < D; d += blockDim.x) { float v = xr[d]; xs[d] = v; sum += v; }
    float mean = block_sum(sum, sbuf) / D;
    float vs = 0;
    for (int d = threadIdx.x; d < D; d += blockDim.x) { float t = xs[d] - mean; vs += t * t; }
    float var = block_sum(vs, sbuf) / D;
    float rstd = rsqrtf(var + 1e-5f);
    for (int d = threadIdx.x; d < D; d += blockDim.x) {
        float v = (xs[d] - mean) * rstd * s[d] + bb[d];
        u16 b16 = f2b(v);
        y[(size_t)row * D + d] = b16;
        if (yT) yT[(size_t)d * NTOK + row] = b16;
    }
}

// ---------------- layernorm bwd (rows cached in LDS) ----------------
__global__ void ln_bwd(const float* __restrict__ dy, const float* __restrict__ x,
                       const float* __restrict__ s, const float* __restrict__ addend,
                       float* __restrict__ dx, u16* __restrict__ dxb, u16* __restrict__ dxT) {
    __shared__ float sbuf[8];
    __shared__ float xs[D];
    __shared__ float dys[D];
    int row = blockIdx.x;
    const float* xr = x + (size_t)row * D;
    const float* dyr = dy + (size_t)row * D;
    float sum = 0;
    for (int d = threadIdx.x; d < D; d += blockDim.x) {
        float v = xr[d]; xs[d] = v; dys[d] = dyr[d]; sum += v;
    }
    float mean = block_sum(sum, sbuf) / D;
    float vs = 0;
    for (int d = threadIdx.x; d < D; d += blockDim.x) { float t = xs[d] - mean; vs += t * t; }
    float var = block_sum(vs, sbuf) / D;
    float rstd = rsqrtf(var + 1e-5f);
    float d1 = 0, d2 = 0;
    for (int d = threadIdx.x; d < D; d += blockDim.x) {
        float xh = (xs[d] - mean) * rstd;
        float t1 = s[d] * dys[d];
        d1 += t1; d2 += t1 * xh;
    }
    float dot1 = block_sum(d1, sbuf);
    float dot2 = block_sum(d2, sbuf);
    for (int d = threadIdx.x; d < D; d += blockDim.x) {
        float xh = (xs[d] - mean) * rstd;
        float t1 = s[d] * dys[d];
        float v = rstd * (t1 - (dot1 + xh * dot2) * (1.f / D));
        if (addend) v += addend[(size_t)row * D + d];
        if (dx) dx[(size_t)row * D + d] = v;
        u16 b16 = f2b(v);
        if (dxb) dxb[(size_t)row * D + d] = b16;
        if (dxT) dxT[(size_t)d * NTOK + row] = b16;
    }
}

// ---------------- head-path layernorm bwd with fused split-K reduce ----------------
__global__ void ln_bwd_head(const float* __restrict__ Cpart, const float* __restrict__ x,
                            const float* __restrict__ s, float* __restrict__ dx,
                            u16* __restrict__ dxb, u16* __restrict__ dxT) {
    __shared__ float sbuf[8];
    __shared__ float xs[D];
    __shared__ float dys[D];
    int row = blockIdx.x;
    float sum = 0;
    for (int d = threadIdx.x; d < D; d += blockDim.x) {
        float a = 0.f;
        for (int z = 0; z < SPLITK; z++)
            a += Cpart[(size_t)z * NTOK * D + (size_t)row * D + d];
        dys[d] = a;
        float v = x[(size_t)row * D + d];
        xs[d] = v;
        sum += v;
    }
    __syncthreads();
    float mean = block_sum(sum, sbuf) / D;
    float vs = 0;
    for (int d = threadIdx.x; d < D; d += blockDim.x) { float t = xs[d] - mean; vs += t * t; }
    float var = block_sum(vs, sbuf) / D;
    float rstd = rsqrtf(var + 1e-5f);
    float d1 = 0, d2 = 0;
    for (int d = threadIdx.x; d < D; d += blockDim.x) {
        float xh = (xs[d] - mean) * rstd;
        float t1 = s[d] * dys[d];
        d1 += t1; d2 += t1 * xh;
    }
    float dot1 = block_sum(d1, sbuf);
    float dot2 = block_sum(d2, sbuf);
    for (int d = threadIdx.x; d < D; d += blockDim.x) {
        float xh = (xs[d] - mean) * rstd;
        float t1 = s[d] * dys[d];
        float v = rstd * (t1 - (dot1 + xh * dot2) * (1.f / D));
        dx[(size_t)row * D + d] = v;
        u16 b16 = f2b(v);
        dxb[(size_t)row * D + d] = b16;
        dxT[(size_t)d * NTOK + row] = b16;
    }
}

// ---------------- attention forward (fp32 core, bf16 O) ----------------
__global__ __launch_bounds__(128) void attn_fwd(const float* __restrict__ qkv,
        float* __restrict__ att, u16* __restrict__ O) {
    int bh = blockIdx.x, b = bh >> 3, h = bh & 7;
    __shared__ float Ks[128][64];
    __shared__ float Vs[128][64];
    for (int idx = threadIdx.x; idx < 128 * 64; idx += 128) {
        int j = idx >> 6, d = idx & 63;
        int row = b * 128 + j;
        Ks[j][d] = qkv[(size_t)row * 1536 + 512 + h * 64 + d];
        Vs[j][d] = qkv[(size_t)row * 1536 + 1024 + h * 64 + d];
    }
    __syncthreads();
    int i = threadIdx.x;
    int row = b * 128 + i;
    float q[64];
#pragma unroll
    for (int d = 0; d < 64; d++) q[d] = qkv[(size_t)row * 1536 + h * 64 + d];
    float* arow = att + ((size_t)bh * 128 + i) * 128;
    float mmax = -1e30f, ssum = 0.f;
    for (int j = 0; j <= i; j++) {
        float sc = 0;
#pragma unroll
        for (int d = 0; d < 64; d++) sc += q[d] * Ks[j][d];
        sc *= 0.125f;
        arow[j] = sc;
        float mn = fmaxf(mmax, sc);
        ssum = ssum * expf(mmax - mn) + expf(sc - mn);
        mmax = mn;
    }
    float inv = 1.f / ssum;
    float o[64];
#pragma unroll
    for (int d = 0; d < 64; d++) o[d] = 0.f;
    for (int j = 0; j < 128; j++) {
        float p = (j <= i) ? expf(arow[j] - mmax) * inv : 0.f;
        arow[j] = p;
#pragma unroll
        for (int d = 0; d < 64; d++) o[d] += p * Vs[j][d];
    }
#pragma unroll
    for (int d = 0; d < 64; d++) O[(size_t)row * 512 + h * 64 + d] = f2b(o[d]);
}

// ---------------- attention backward, fused (dS via global, dq/dk/dv bf16) ----------------
__global__ __launch_bounds__(128) void attn_bwd(const float* __restrict__ qkv,
        const float* __restrict__ att, const float* __restrict__ dO,
        float* __restrict__ dS, u16* __restrict__ dqkv) {
    int bh = blockIdx.x, b = bh >> 3, h = bh & 7;
    __shared__ float Ks[128][64];   // phase A: K, phase B: Q
    __shared__ float Vs[128][64];   // phase A: V, phase B: dO
    for (int idx = threadIdx.x; idx < 128 * 64; idx += 128) {
        int j = idx >> 6, d = idx & 63;
        int row = b * 128 + j;
        Ks[j][d] = qkv[(size_t)row * 1536 + 512 + h * 64 + d];
        Vs[j][d] = qkv[(size_t)row * 1536 + 1024 + h * 64 + d];
    }
    __syncthreads();
    {   // ---- phase A: per-row dS + dq ----
        int i = threadIdx.x;
        int row = b * 128 + i;
        float dOi[64];
#pragma unroll
        for (int d = 0; d < 64; d++) dOi[d] = dO[(size_t)row * 512 + h * 64 + d];
        const float* arow = att + ((size_t)bh * 128 + i) * 128;
        float* dsrow = dS + ((size_t)bh * 128 + i) * 128;
        float rowdot = 0.f;
        for (int j = 0; j <= i; j++) {
            float dA = 0;
#pragma unroll
            for (int d = 0; d < 64; d++) dA += dOi[d] * Vs[j][d];
            dsrow[j] = dA;
            rowdot += dA * arow[j];
        }
        float dq[64];
#pragma unroll
        for (int d = 0; d < 64; d++) dq[d] = 0.f;
        for (int j = 0; j <= i; j++) {
            float ds = arow[j] * (dsrow[j] - rowdot);
            dsrow[j] = ds;
#pragma unroll
            for (int d = 0; d < 64; d++) dq[d] += ds * Ks[j][d];
        }
#pragma unroll
        for (int d = 0; d < 64; d++)
            dqkv[(size_t)row * 1536 + h * 64 + d] = f2b(dq[d] * 0.125f);
    }
    __syncthreads();
    // reload: Q -> Ks, dO -> Vs
    for (int idx = threadIdx.x; idx < 128 * 64; idx += 128) {
        int j = idx >> 6, d = idx & 63;
        int row = b * 128 + j;
        Ks[j][d] = qkv[(size_t)row * 1536 + h * 64 + d];
        Vs[j][d] = dO[(size_t)row * 512 + h * 64 + d];
    }
    __syncthreads();
    {   // ---- phase B: per-col dk, dv ----
        int j = threadIdx.x;
        float dk[64], dv[64];
#pragma unroll
        for (int d = 0; d < 64; d++) { dk[d] = 0.f; dv[d] = 0.f; }
        for (int i = j; i < 128; i++) {
            float a_ = att[((size_t)bh * 128 + i) * 128 + j];
            float ds = dS[((size_t)bh * 128 + i) * 128 + j];
#pragma unroll
            for (int d = 0; d < 64; d++) { dv[d] += a_ * Vs[i][d]; dk[d] += ds * Ks[i][d]; }
        }
        int row = b * 128 + j;
#pragma unroll
        for (int d = 0; d < 64; d++) {
            dqkv[(size_t)row * 1536 + 512 + h * 64 + d] = f2b(dk[d] * 0.125f);
            dqkv[(size_t)row * 1536 + 1024 + h * 64 + d] = f2b(dv[d]);
        }
    }
}

// ---------------- cross-entropy gradient: 2 passes, vectorized ----------------
__global__ void ce_grad(const float* __restrict__ outbuf, const int* __restrict__ x,
                        u16* __restrict__ dl, int c) {
    __shared__ float sbuf[8];
    int n = blockIdx.x;
    int b = n >> 7, i = n & 127;
    int tgt = x[b * T + c * MB + i + 1];
    const float* lrow = outbuf + ((size_t)(b * 1024 + c * MB + i)) * V;
    const f32x4* l4 = (const f32x4*)lrow;
    float mx = -1e30f, se = 0.f;
    for (int v = threadIdx.x; v < V / 4; v += blockDim.x) {
        f32x4 q = l4[v];
#pragma unroll
        for (int e = 0; e < 4; e++) {
            float t = q[e];
            if (t > mx) { se = se * expf(mx - t) + 1.f; mx = t; }
            else se += expf(t - mx);
        }
    }
    float M = block_max(mx, sbuf);
    se *= expf(mx - M);
    float S = block_sum(se, sbuf);
    float inv = 1.f / S;
    u16x4* d4 = (u16x4*)(dl + (size_t)n * V);
    for (int v = threadIdx.x; v < V / 4; v += blockDim.x) {
        f32x4 q = l4[v];
        u16x4 o;
#pragma unroll
        for (int e = 0; e < 4; e++) {
            int idx = 4 * v + e;
            float p = expf(q[e] - M) * inv;
            o[e] = f2b((p - (idx == tgt ? 1.f : 0.f)) * (1.f / 256.f));
        }
        d4[v] = o;
    }
}

// ---------------- host orchestration ----------------
extern "C" void kernel_launch(void* const* d_in, const int* in_sizes, int n_in,
                              void* d_out, int out_size, void* d_ws, size_t ws_size,
                              hipStream_t stream) {
    const int* x = (const int*)d_in[0];
    const float* emb = (const float*)d_in[1];
    const float* pos = (const float*)d_in[2];
    const float* ln1_s = (const float*)d_in[3];
    const float* ln1_b = (const float*)d_in[4];
    const float* Wqkv = (const float*)d_in[5];
    const float* bqkv = (const float*)d_in[6];
    const float* Wo = (const float*)d_in[7];
    const float* bo = (const float*)d_in[8];
    const float* ln2_s = (const float*)d_in[9];
    const float* ln2_b = (const float*)d_in[10];
    const float* W1in = (const float*)d_in[11];
    const float* b1in = (const float*)d_in[12];
    const float* W2in = (const float*)d_in[13];
    const float* b2in = (const float*)d_in[14];
    const float* lnf_s = (const float*)d_in[15];
    const float* lnf_b = (const float*)d_in[16];
    const float* Whead = (const float*)d_in[17];
    const float* bhead = (const float*)d_in[18];
    float* out = (float*)d_out;

    float* ws = (float*)d_ws;
    size_t off = 0;
    auto alloc4 = [&](size_t n) { float* p = ws + off; off += (n + 3) & ~(size_t)3; return p; };
    auto allocH = [&](size_t n) { return (u16*)alloc4((n + 1) / 2); };

    // fp32 masters for trained params
    float* W1m = alloc4((size_t)LAYERS * D * HID);
    float* W2m = alloc4((size_t)LAYERS * HID * D);
    float* b1w = alloc4((size_t)LAYERS * HID);
    float* b2w = alloc4((size_t)LAYERS * D);
    // bf16 weight copies (natural + transposed)
    u16* W1n = allocH((size_t)LAYERS * D * HID);
    u16* W1t = allocH((size_t)LAYERS * D * HID);
    u16* W2n = allocH((size_t)LAYERS * HID * D);
    u16* W2t = allocH((size_t)LAYERS * HID * D);
    u16* Wqkv_n = allocH((size_t)LAYERS * D * 3 * D);
    u16* Wqkv_t = allocH((size_t)LAYERS * D * 3 * D);
    u16* Wo_n = allocH((size_t)LAYERS * D * D);
    u16* Wo_t = allocH((size_t)LAYERS * D * D);
    u16* Whead_n = allocH((size_t)D * V);
    u16* Whead_t = allocH((size_t)D * V);
    // activations
    float* h[5]; for (int i = 0; i < 5; i++) h[i] = alloc4((size_t)NTOK * D);
    float* hp[4]; for (int i = 0; i < 4; i++) hp[i] = alloc4((size_t)NTOK * D);
    u16* a_bf = allocH((size_t)NTOK * D);
    float* qkvb[4]; for (int i = 0; i < 4; i++) qkvb[i] = alloc4((size_t)NTOK * 3 * D);
    float* attb[4]; for (int i = 0; i < 4; i++) attb[i] = alloc4((size_t)BATCH * NH * MB * MB);
    u16* O_bf = allocH((size_t)NTOK * D);
    u16* mb_bf[4]; for (int i = 0; i < 4; i++) mb_bf[i] = allocH((size_t)NTOK * D);
    u16* mbT[4]; for (int i = 0; i < 4; i++) mbT[i] = allocH((size_t)D * NTOK);
    float* gbuf[4]; for (int i = 0; i < 4; i++) gbuf[i] = alloc4((size_t)NTOK * HID);
    u16* u_bf[4]; for (int i = 0; i < 4; i++) u_bf[i] = allocH((size_t)NTOK * HID);
    u16* uT[4]; for (int i = 0; i < 4; i++) uT[i] = allocH((size_t)HID * NTOK);
    u16* af_bf = allocH((size_t)NTOK * D);
    u16* dlog_bf = allocH((size_t)NTOK * V);
    float* Cpart = alloc4((size_t)SPLITK * NTOK * D);
    float* t512 = alloc4((size_t)NTOK * D);
    float* dh = alloc4((size_t)NTOK * D);
    u16* dh_bf = allocH((size_t)NTOK * D);
    u16* dhT = allocH((size_t)D * NTOK);
    float* dhp = alloc4((size_t)NTOK * D);
    u16* dhp_bf = allocH((size_t)NTOK * D);
    u16* dg_bf = allocH((size_t)NTOK * HID);
    u16* dgT = allocH((size_t)HID * NTOK);
    u16* dqkv_bf = allocH((size_t)NTOK * 3 * D);
    float* dS = alloc4((size_t)BATCH * NH * MB * MB);

    dim3 blk256(256);

    // ---- one-time (per launch) weight conversions ----
    hipMemcpyAsync(W1m, W1in, (size_t)LAYERS * D * HID * 4, hipMemcpyDeviceToDevice, stream);
    hipMemcpyAsync(W2m, W2in, (size_t)LAYERS * HID * D * 4, hipMemcpyDeviceToDevice, stream);
    hipMemcpyAsync(b1w, b1in, (size_t)LAYERS * HID * 4, hipMemcpyDeviceToDevice, stream);
    hipMemcpyAsync(b2w, b2in, (size_t)LAYERS * D * 4, hipMemcpyDeviceToDevice, stream);
    for (int l = 0; l < LAYERS; l++) {
        conv_nt<<<dim3(1536 / 64, 512 / 64), blk256, 0, stream>>>(
            Wqkv + (size_t)l * D * 1536, Wqkv_n + (size_t)l * D * 1536,
            Wqkv_t + (size_t)l * D * 1536, 512, 1536);
        conv_nt<<<dim3(8, 8), blk256, 0, stream>>>(
            Wo + (size_t)l * D * D, Wo_n + (size_t)l * D * D,
            Wo_t + (size_t)l * D * D, 512, 512);
        conv_nt<<<dim3(32, 8), blk256, 0, stream>>>(
            W1in + (size_t)l * D * HID, W1n + (size_t)l * D * HID,
            W1t + (size_t)l * D * HID, 512, 2048);
        conv_nt<<<dim3(8, 32), blk256, 0, stream>>>(
            W2in + (size_t)l * HID * D, W2n + (size_t)l * HID * D,
            W2t + (size_t)l * HID * D, 2048, 512);
    }
    conv_nt<<<dim3(500, 8), blk256, 0, stream>>>(Whead, Whead_n, Whead_t, 512, 32000);

    // gemm helper: C = A[MxK] * Bt[NxK]^T
    auto G = [&](const u16* A, int lda, const u16* Bt, int ldb, float* C, int ldc,
                 int M, int N, int K, const float* bias, const float* res, int ldres,
                 int remapc) {
        gemm64<<<dim3(N / 64, M / 64), blk256, 0, stream>>>(
            A, lda, Bt, ldb, C, ldc, K, 0, bias, res, ldres, remapc);
    };

    for (int c = 0; c < NCHUNK; c++) {
        // ================ forward ================
        embed_ln<<<NTOK, blk256, 0, stream>>>(x, emb, pos, ln1_s, ln1_b, h[0], a_bf, c);
        for (int l = 0; l < LAYERS; l++) {
            if (l > 0)
                ln_fwd<<<NTOK, blk256, 0, stream>>>(h[l], ln1_s + l * D, ln1_b + l * D,
                                                    a_bf, nullptr);
            G(a_bf, D, Wqkv_t + (size_t)l * D * 1536, D, qkvb[l], 1536,
              NTOK, 1536, D, bqkv + l * 1536, nullptr, 0, -1);
            attn_fwd<<<16, 128, 0, stream>>>(qkvb[l], attb[l], O_bf);
            G(O_bf, D, Wo_t + (size_t)l * D * D, D, hp[l], D,
              NTOK, D, D, bo + l * D, h[l], D, -1);
            ln_fwd<<<NTOK, blk256, 0, stream>>>(hp[l], ln2_s + l * D, ln2_b + l * D,
                                                mb_bf[l], mbT[l]);
            gemm64_gelu<<<dim3(HID / 64, NTOK / 64), blk256, 0, stream>>>(
                mb_bf[l], D, W1t + (size_t)l * D * HID, D, D,
                b1w + l * HID, gbuf[l], u_bf[l], uT[l]);
            G(u_bf[l], HID, W2t + (size_t)l * D * HID, HID, h[l + 1], D,
              NTOK, D, HID, b2w + l * D, hp[l], D, -1);
        }
        ln_fwd<<<NTOK, blk256, 0, stream>>>(h[4], lnf_s, lnf_b, af_bf, nullptr);
        // head GEMM writes directly into d_out with chunk row remap
        G(af_bf, D, Whead_t, D, out, V, NTOK, V, D, bhead, nullptr, 0, c);

        // ================ backward ================
        ce_grad<<<NTOK, blk256, 0, stream>>>(out, x, dlog_bf, c);
        // dX partials = dlog @ Whead^T  (split-K over V)
        gemm64<<<dim3(D / 64, NTOK / 64, SPLITK), blk256, 0, stream>>>(
            dlog_bf, V, Whead_n, V, Cpart, D, SKLEN, NTOK * D,
            nullptr, nullptr, 0, -1);
        ln_bwd_head<<<NTOK, blk256, 0, stream>>>(Cpart, h[4], lnf_s, dh, dh_bf, dhT);
        for (int l = LAYERS - 1; l >= 0; l--) {
            // ---- MLP backward ----
            gemm64_dgelu<<<dim3(HID / 64, NTOK / 64), blk256, 0, stream>>>(
                dh_bf, D, W2n + (size_t)l * HID * D, D, D, gbuf[l], dg_bf, dgT);
            gemm64_upd<<<dim3(D / 64, HID / 64), blk256, 0, stream>>>(
                uT[l], NTOK, dhT, NTOK, W2m + (size_t)l * HID * D, D, NTOK, LR,
                W2n + (size_t)l * HID * D, W2t + (size_t)l * HID * D, HID, b2w + l * D);
            gemm64_upd<<<dim3(HID / 64, D / 64), blk256, 0, stream>>>(
                mbT[l], NTOK, dgT, NTOK, W1m + (size_t)l * D * HID, HID, NTOK, LR,
                W1n + (size_t)l * D * HID, W1t + (size_t)l * D * HID, D, b1w + l * HID);
            G(dg_bf, HID, W1n + (size_t)l * D * HID, HID, t512, D,
              NTOK, D, HID, nullptr, nullptr, 0, -1);
            ln_bwd<<<NTOK, blk256, 0, stream>>>(t512, hp[l], ln2_s + l * D, dh,
                                                dhp, dhp_bf, nullptr);
            // ---- attention backward ----
            G(dhp_bf, D, Wo_n + (size_t)l * D * D, D, t512, D,
              NTOK, D, D, nullptr, nullptr, 0, -1);
            attn_bwd<<<16, 128, 0, stream>>>(qkvb[l], attb[l], t512, dS, dqkv_bf);
            G(dqkv_bf, 1536, Wqkv_n + (size_t)l * D * 1536, 1536, t512, D,
              NTOK, D, 1536, nullptr, nullptr, 0, -1);
            if (l > 0)
                ln_bwd<<<NTOK, blk256, 0, stream>>>(t512, h[l], ln1_s + l * D, dhp,
                                                    dh, dh_bf, dhT);
        }
    }
}

// Round 2
// 11933.342 us; speedup vs baseline: 1.5459x; 1.3016x over previous
//
#include <hip/hip_runtime.h>
#include <hip/hip_bf16.h>
#include <math.h>

#define D 512
#define HID 2048
#define LAYERS 4
#define V 32000
#define BATCH 2
#define T 1025
#define MB 128
#define NH 8
#define DH 64
#define NTOK 256            // BATCH*MB rows per chunk
#define LR 0.0003f
#define NCHUNK 8
#define SPLITK 25
#define SKLEN 1280          // 32000 / 25, multiple of 128

typedef unsigned short u16;
typedef __attribute__((ext_vector_type(8))) short bf16x8;
typedef __attribute__((ext_vector_type(4))) float f32x4;
typedef __attribute__((ext_vector_type(4))) unsigned short u16x4;

// ---- fp32 <-> bf16 (RNE) ----
__device__ __forceinline__ u16 f2b(float f) {
    unsigned int x = __float_as_uint(f);
    unsigned int r = (x + 0x7FFFu + ((x >> 16) & 1u)) >> 16;
    return (u16)r;
}
__device__ __forceinline__ float b2f(u16 u) {
    return __uint_as_float(((unsigned int)u) << 16);
}

// ---- async global->LDS 16B ----
__device__ __forceinline__ void gload16(const u16* g, u16* l) {
    __builtin_amdgcn_global_load_lds(
        (const __attribute__((address_space(1))) unsigned int*)g,
        (__attribute__((address_space(3))) unsigned int*)l, 16, 0, 0);
}

// =================== MFMA GEMM core, BK=128 ===================
// C[M][N] = A[M][K] * Bt[N][K]^T ; A,Bt bf16 K-contiguous. 64x64 tile.
// K staged as two 64-wide halves, each in the proven 64x64 swizzled layout.
// As, Bs: 8192 u16 each (16 KB). kBegin/kEnd multiples of 128.
__device__ __forceinline__ void gemm_core(
    const u16* __restrict__ A, int lda, const u16* __restrict__ Bt, int ldb,
    int kBegin, int kEnd, int m0, int n0, u16* As, u16* Bs, f32x4 acc[2][2])
{
    int t = threadIdx.x, w = t >> 6, l = t & 63;
    int srow = w * 8 + (l >> 3);     // staging row 0..31 (+32 second half)
    int qs = l & 7;                  // LDS quad slot
    int gq = qs ^ (srow & 7);        // swizzled global quad
    const u16* Ag = A + (size_t)(m0 + srow) * lda + gq * 8;
    const u16* Bg = Bt + (size_t)(n0 + srow) * ldb + gq * 8;
    u16* AsP = As + srow * 64 + qs * 8;
    u16* BsP = Bs + srow * 64 + qs * 8;
    size_t a32 = (size_t)32 * lda, b32 = (size_t)32 * ldb;
    int fr = l & 15, fq = l >> 4;
    int wr = (w >> 1) * 32, wc = (w & 1) * 32;  // wave sub-tile
    const u16* arp = As + (size_t)(wr + fr) * 64;
    const u16* brp = Bs + (size_t)(wc + fr) * 64;
    int sw = fr & 7;
    for (int k0 = kBegin; k0 < kEnd; k0 += 128) {
        if (k0 != kBegin) __syncthreads();
#pragma unroll
        for (int hh = 0; hh < 2; hh++) {
            int kg = k0 + hh * 64;
            gload16(Ag + kg, AsP + hh * 4096);
            gload16(Ag + a32 + kg, AsP + hh * 4096 + 2048);
            gload16(Bg + kg, BsP + hh * 4096);
            gload16(Bg + b32 + kg, BsP + hh * 4096 + 2048);
        }
        __syncthreads();
#pragma unroll
        for (int kk = 0; kk < 4; kk++) {
            int sq = (((kk & 1) * 4 + fq) ^ sw) * 8 + (kk >> 1) * 4096;
            bf16x8 a0 = *(const bf16x8*)(arp + sq);
            bf16x8 a1 = *(const bf16x8*)(arp + 16 * 64 + sq);
            bf16x8 b0 = *(const bf16x8*)(brp + sq);
            bf16x8 b1 = *(const bf16x8*)(brp + 16 * 64 + sq);
            acc[0][0] = __builtin_amdgcn_mfma_f32_16x16x32_bf16(a0, b0, acc[0][0], 0, 0, 0);
            acc[0][1] = __builtin_amdgcn_mfma_f32_16x16x32_bf16(a0, b1, acc[0][1], 0, 0, 0);
            acc[1][0] = __builtin_amdgcn_mfma_f32_16x16x32_bf16(a1, b0, acc[1][0], 0, 0, 0);
            acc[1][1] = __builtin_amdgcn_mfma_f32_16x16x32_bf16(a1, b1, acc[1][1], 0, 0, 0);
        }
    }
}

// ---- generic GEMM body: optional bias, residual, chunk-row-remap, split-K ----
__device__ __forceinline__ void gemm_body(int bx, int by, int bz,
    const u16* __restrict__ A, int lda, const u16* __restrict__ Bt, int ldb,
    float* __restrict__ C, int ldc, int kLen, int zStride,
    const float* __restrict__ bias, const float* __restrict__ res, int ldres,
    int remapc, u16* S)
{
    u16* As = S; u16* Bs = S + 8192;
    f32x4 zero = {0.f, 0.f, 0.f, 0.f};
    f32x4 acc[2][2] = {{zero, zero}, {zero, zero}};
    int m0 = by * 64, n0 = bx * 64;
    gemm_core(A, lda, Bt, ldb, bz * kLen, bz * kLen + kLen, m0, n0, As, Bs, acc);
    float* Cz = C + (size_t)bz * zStride;
    int l = threadIdx.x & 63, w = threadIdx.x >> 6;
    int wr = (w >> 1) * 32, wc = (w & 1) * 32;
    int cn = n0 + wc + (l & 15);
    int rb = wr + (l >> 4) * 4;
#pragma unroll
    for (int i = 0; i < 2; i++)
#pragma unroll
        for (int r = 0; r < 4; r++) {
            int m = m0 + rb + i * 16 + r;
            int mo = (remapc >= 0) ? ((m >> 7) * 1024 + remapc * 128 + (m & 127)) : m;
#pragma unroll
            for (int j = 0; j < 2; j++) {
                int n = cn + j * 16;
                float v = acc[i][j][r];
                if (bias) v += bias[n];
                if (res) v += res[(size_t)m * ldres + n];
                Cz[(size_t)mo * ldc + n] = v;
            }
        }
}

__global__ __launch_bounds__(256) void gemm64(
    const u16* __restrict__ A, int lda, const u16* __restrict__ Bt, int ldb,
    float* __restrict__ C, int ldc, int kLen, int zStride,
    const float* __restrict__ bias, const float* __restrict__ res, int ldres, int remapc)
{
    __shared__ __align__(16) u16 S[16384];
    gemm_body(blockIdx.x, blockIdx.y, blockIdx.z, A, lda, Bt, ldb, C, ldc,
              kLen, zStride, bias, res, ldres, remapc, S);
}

// ---- FF1 GEMM + bias + gelu fused ----
__global__ __launch_bounds__(256) void gemm64_gelu(
    const u16* __restrict__ A, int lda, const u16* __restrict__ Bt, int ldb, int K,
    const float* __restrict__ bias, float* __restrict__ gout,
    u16* __restrict__ u, u16* __restrict__ uT)
{
    __shared__ __align__(16) u16 S[16384];
    u16* As = S; u16* Bs = S + 8192;
    f32x4 zero = {0.f, 0.f, 0.f, 0.f};
    f32x4 acc[2][2] = {{zero, zero}, {zero, zero}};
    int m0 = blockIdx.y * 64, n0 = blockIdx.x * 64;
    gemm_core(A, lda, Bt, ldb, 0, K, m0, n0, As, Bs, acc);
    int t = threadIdx.x, l = t & 63, w = t >> 6;
    int wr = (w >> 1) * 32, wc = (w & 1) * 32;
    int cnl = wc + (l & 15);
    int rbl = wr + (l >> 4) * 4;
    __syncthreads();           // done reading staging LDS
    u16* Ts = S;               // [64 n][72] bf16 tile for transposed store
#pragma unroll
    for (int i = 0; i < 2; i++)
#pragma unroll
        for (int r = 0; r < 4; r++) {
            int ml = rbl + i * 16 + r;
            size_t grow = (size_t)(m0 + ml) * HID;
#pragma unroll
            for (int j = 0; j < 2; j++) {
                int nl = cnl + j * 16;
                float v = acc[i][j][r] + bias[n0 + nl];
                gout[grow + n0 + nl] = v;
                float th = tanhf(0.7978845608028654f * (v + 0.044715f * v * v * v));
                u16 bb = f2b(0.5f * v * (1.f + th));
                u[grow + n0 + nl] = bb;
                Ts[nl * 72 + ml] = bb;
            }
        }
    __syncthreads();
    int cc = t >> 2, rs = (t & 3) * 16;
    u16* opT = uT + (size_t)(n0 + cc) * NTOK + m0 + rs;
#pragma unroll
    for (int k2 = 0; k2 < 16; k2++) opT[k2] = Ts[cc * 72 + rs + k2];
}

// ---- du GEMM + gelu-bwd fused ----
__global__ __launch_bounds__(256) void gemm64_dgelu(
    const u16* __restrict__ A, int lda, const u16* __restrict__ Bt, int ldb, int K,
    const float* __restrict__ g, u16* __restrict__ dg, u16* __restrict__ dgT)
{
    __shared__ __align__(16) u16 S[16384];
    u16* As = S; u16* Bs = S + 8192;
    f32x4 zero = {0.f, 0.f, 0.f, 0.f};
    f32x4 acc[2][2] = {{zero, zero}, {zero, zero}};
    int m0 = blockIdx.y * 64, n0 = blockIdx.x * 64;
    gemm_core(A, lda, Bt, ldb, 0, K, m0, n0, As, Bs, acc);
    int t = threadIdx.x, l = t & 63, w = t >> 6;
    int wr = (w >> 1) * 32, wc = (w & 1) * 32;
    int cnl = wc + (l & 15);
    int rbl = wr + (l >> 4) * 4;
    __syncthreads();
    u16* Ts = S;
#pragma unroll
    for (int i = 0; i < 2; i++)
#pragma unroll
        for (int r = 0; r < 4; r++) {
            int ml = rbl + i * 16 + r;
            size_t grow = (size_t)(m0 + ml) * HID;
#pragma unroll
            for (int j = 0; j < 2; j++) {
                int nl = cnl + j * 16;
                float x = g[grow + n0 + nl];
                const float cc_ = 0.7978845608028654f, a = 0.044715f;
                float th = tanhf(cc_ * (x + a * x * x * x));
                float dt = (1.f - th * th) * cc_ * (1.f + 3.f * a * x * x);
                float grad = 0.5f * (1.f + th) + 0.5f * x * dt;
                u16 bb = f2b(acc[i][j][r] * grad);
                dg[grow + n0 + nl] = bb;
                Ts[nl * 72 + ml] = bb;
            }
        }
    __syncthreads();
    int cc = t >> 2, rs = (t & 3) * 16;
    u16* opT = dgT + (size_t)(n0 + cc) * NTOK + m0 + rs;
#pragma unroll
    for (int k2 = 0; k2 < 16; k2++) opT[k2] = Ts[cc * 72 + rs + k2];
}

// ---- TN weight-update GEMM body: P -= lr*acc; refresh bf16 N+T copies; fused bias ----
__device__ __forceinline__ void upd_body(int bx, int by,
    const u16* __restrict__ A, int lda, const u16* __restrict__ Bt, int ldb,
    float* __restrict__ P, int ldp, int K, float lr,
    u16* __restrict__ Wn, u16* __restrict__ Wt, int ldt, float* __restrict__ bias,
    u16* S)
{
    u16* As = S; u16* Bs = S + 8192;
    f32x4 zero = {0.f, 0.f, 0.f, 0.f};
    f32x4 acc[2][2] = {{zero, zero}, {zero, zero}};
    int m0 = by * 64, n0 = bx * 64;
    gemm_core(A, lda, Bt, ldb, 0, K, m0, n0, As, Bs, acc);
    int t = threadIdx.x, l = t & 63, w = t >> 6;
    int wr = (w >> 1) * 32, wc = (w & 1) * 32;
    int cnl = wc + (l & 15);
    int rbl = wr + (l >> 4) * 4;
    __syncthreads();
    u16* Ts = S;
#pragma unroll
    for (int i = 0; i < 2; i++)
#pragma unroll
        for (int r = 0; r < 4; r++) {
            int ml = rbl + i * 16 + r;
            int m = m0 + ml;
#pragma unroll
            for (int j = 0; j < 2; j++) {
                int nl = cnl + j * 16;
                int n = n0 + nl;
                size_t ip = (size_t)m * ldp + n;
                float nv = P[ip] - lr * acc[i][j][r];
                P[ip] = nv;
                u16 bb = f2b(nv);
                Wn[ip] = bb;
                Ts[nl * 72 + ml] = bb;
            }
        }
    __syncthreads();
    int cc = t >> 2, rs = (t & 3) * 16;
    u16* opT = Wt + (size_t)(n0 + cc) * ldt + m0 + rs;
#pragma unroll
    for (int k2 = 0; k2 < 16; k2++) opT[k2] = Ts[cc * 72 + rs + k2];
    // fused bias update: bias[n] -= lr * sum_k Bt[n][k]   (K == NTOK == 256)
    if (bias && m0 == 0) {
        int nl = t >> 2, ks = (t & 3) * 64;
        const u16* bp = Bt + (size_t)(n0 + nl) * ldb + ks;
        float s = 0.f;
#pragma unroll
        for (int k = 0; k < 64; k += 8) {
            bf16x8 v8 = *(const bf16x8*)(bp + k);
#pragma unroll
            for (int e = 0; e < 8; e++) s += b2f((u16)v8[e]);
        }
        s += __shfl_xor(s, 1, 64);
        s += __shfl_xor(s, 2, 64);
        if ((t & 3) == 0) bias[n0 + nl] -= lr * s;
    }
}

// ---- fp32 [R][C] -> bf16 natural + transposed, 64x64 tiles (one-time) ----
__global__ __launch_bounds__(256) void conv_nt(const float* __restrict__ in,
        u16* __restrict__ outN, u16* __restrict__ outT, int R, int C) {
    __shared__ u16 Ts[64][72];
    int c0 = blockIdx.x * 64, r0 = blockIdx.y * 64;
    int t = threadIdx.x, lr = t >> 2, cs = (t & 3) * 16;
    const float* ip = in + (size_t)(r0 + lr) * C + c0 + cs;
    u16* op = outN + (size_t)(r0 + lr) * C + c0 + cs;
#pragma unroll
    for (int k = 0; k < 16; k++) {
        u16 bb = f2b(ip[k]);
        op[k] = bb;
        Ts[lr][cs + k] = bb;
    }
    __syncthreads();
    int cc = t >> 2, rs = (t & 3) * 16;
    u16* opT = outT + (size_t)(c0 + cc) * R + r0 + rs;
#pragma unroll
    for (int k = 0; k < 16; k++) opT[k] = Ts[rs + k][cc];
}

// ---------------- reductions ----------------
__device__ __forceinline__ float block_sum(float v, float* sbuf) {
    int t = threadIdx.x;
    for (int o = 32; o > 0; o >>= 1) v += __shfl_down(v, o, 64);
    if ((t & 63) == 0) sbuf[t >> 6] = v;
    __syncthreads();
    int nw = blockDim.x >> 6;
    float r = (t < nw) ? sbuf[t] : 0.f;
    if (t < 64) { for (int o = 32; o > 0; o >>= 1) r += __shfl_down(r, o, 64); }
    if (t == 0) sbuf[0] = r;
    __syncthreads();
    float out = sbuf[0];
    __syncthreads();
    return out;
}
__device__ __forceinline__ float block_max(float v, float* sbuf) {
    int t = threadIdx.x;
    for (int o = 32; o > 0; o >>= 1) v = fmaxf(v, __shfl_down(v, o, 64));
    if ((t & 63) == 0) sbuf[t >> 6] = v;
    __syncthreads();
    int nw = blockDim.x >> 6;
    float r = (t < nw) ? sbuf[t] : -1e30f;
    if (t < 64) { for (int o = 32; o > 0; o >>= 1) r = fmaxf(r, __shfl_down(r, o, 64)); }
    if (t == 0) sbuf[0] = r;
    __syncthreads();
    float out = sbuf[0];
    __syncthreads();
    return out;
}

// ---------------- embedding + layer-0 ln1, all chunks precomputed ----------------
__global__ void embed_ln_all(const int* __restrict__ x, const float* __restrict__ emb,
                             const float* __restrict__ pos, const float* __restrict__ s,
                             const float* __restrict__ bb, float* __restrict__ h0all,
                             u16* __restrict__ yall) {
    __shared__ float sbuf[8];
    __shared__ float xs[D];
    int n = blockIdx.x, c = blockIdx.y;
    int b = n >> 7, i = n & 127;
    int tok = x[b * T + c * MB + i];
    float* h0 = h0all + (size_t)c * NTOK * D;
    u16* y = yall + (size_t)c * NTOK * D;
    float sum = 0.f;
    for (int d = threadIdx.x; d < D; d += blockDim.x) {
        float v = emb[(size_t)tok * D + d] + pos[(size_t)i * D + d];
        xs[d] = v;
        h0[(size_t)n * D + d] = v;
        sum += v;
    }
    __syncthreads();
    float mean = block_sum(sum, sbuf) / D;
    float vs = 0.f;
    for (int d = threadIdx.x; d < D; d += blockDim.x) { float t = xs[d] - mean; vs += t * t; }
    float var = block_sum(vs, sbuf) / D;
    float rstd = rsqrtf(var + 1e-5f);
    for (int d = threadIdx.x; d < D; d += blockDim.x)
        y[(size_t)n * D + d] = f2b((xs[d] - mean) * rstd * s[d] + bb[d]);
}

// ---------------- layernorm fwd (row cached in LDS) ----------------
__global__ void ln_fwd(const float* __restrict__ x, const float* __restrict__ s,
                       const float* __restrict__ bb, u16* __restrict__ y,
                       u16* __restrict__ yT) {
    __shared__ float sbuf[8];
    __shared__ float xs[D];
    int row = blockIdx.x;
    const float* xr = x + (size_t)row * D;
    float sum = 0;
    for (int d = threadIdx.x; d < D; d += blockDim.x) { float v = xr[d]; xs[d] = v; sum += v; }
    float mean = block_sum(sum, sbuf) / D;
    float vs = 0;
    for (int d = threadIdx.x; d < D; d += blockDim.x) { float t = xs[d] - mean; vs += t * t; }
    float var = block_sum(vs, sbuf) / D;
    float rstd = rsqrtf(var + 1e-5f);
    for (int d = threadIdx.x; d < D; d += blockDim.x) {
        float v = (xs[d] - mean) * rstd * s[d] + bb[d];
        u16 b16 = f2b(v);
        y[(size_t)row * D + d] = b16;
        if (yT) yT[(size_t)d * NTOK + row] = b16;
    }
}

// ---- layernorm fwd over (sum of split-K partials + residual + bias); writes h ----
__global__ void ln_fwd_sum(const float* __restrict__ Cp, int nPart,
                           const float* __restrict__ res, const float* __restrict__ bias,
                           float* __restrict__ hout, const float* __restrict__ s,
                           const float* __restrict__ bb, u16* __restrict__ y) {
    __shared__ float sbuf[8];
    __shared__ float xs[D];
    int row = blockIdx.x;
    float sum = 0.f;
    for (int d = threadIdx.x; d < D; d += blockDim.x) {
        float a = res[(size_t)row * D + d] + bias[d];
        for (int z = 0; z < nPart; z++)
            a += Cp[(size_t)z * NTOK * D + (size_t)row * D + d];
        xs[d] = a;
        hout[(size_t)row * D + d] = a;
        sum += a;
    }
    __syncthreads();
    float mean = block_sum(sum, sbuf) / D;
    float vs = 0.f;
    for (int d = threadIdx.x; d < D; d += blockDim.x) { float t = xs[d] - mean; vs += t * t; }
    float var = block_sum(vs, sbuf) / D;
    float rstd = rsqrtf(var + 1e-5f);
    for (int d = threadIdx.x; d < D; d += blockDim.x)
        y[(size_t)row * D + d] = f2b((xs[d] - mean) * rstd * s[d] + bb[d]);
}

// ---------------- layernorm bwd body (dy = sum of nPart partials) ----------------
__device__ __forceinline__ void lnbwd_body(int row, const float* __restrict__ dyP,
    int nPart, int pStride, const float* __restrict__ x, const float* __restrict__ s,
    const float* __restrict__ addend, float* __restrict__ dx, u16* __restrict__ dxb,
    u16* __restrict__ dxT, float* xs, float* dys, float* sbuf)
{
    const float* xr = x + (size_t)row * D;
    float sum = 0;
    for (int d = threadIdx.x; d < D; d += blockDim.x) {
        float v = xr[d]; xs[d] = v; sum += v;
        float a = 0.f;
        for (int z = 0; z < nPart; z++)
            a += dyP[(size_t)z * pStride + (size_t)row * D + d];
        dys[d] = a;
    }
    float mean = block_sum(sum, sbuf) / D;
    float vs = 0;
    for (int d = threadIdx.x; d < D; d += blockDim.x) { float t = xs[d] - mean; vs += t * t; }
    float var = block_sum(vs, sbuf) / D;
    float rstd = rsqrtf(var + 1e-5f);
    float d1 = 0, d2 = 0;
    for (int d = threadIdx.x; d < D; d += blockDim.x) {
        float xh = (xs[d] - mean) * rstd;
        float t1 = s[d] * dys[d];
        d1 += t1; d2 += t1 * xh;
    }
    float dot1 = block_sum(d1, sbuf);
    float dot2 = block_sum(d2, sbuf);
    for (int d = threadIdx.x; d < D; d += blockDim.x) {
        float xh = (xs[d] - mean) * rstd;
        float t1 = s[d] * dys[d];
        float v = rstd * (t1 - (dot1 + xh * dot2) * (1.f / D));
        if (addend) v += addend[(size_t)row * D + d];
        if (dx) dx[(size_t)row * D + d] = v;
        u16 b16 = f2b(v);
        if (dxb) dxb[(size_t)row * D + d] = b16;
        if (dxT) dxT[(size_t)d * NTOK + row] = b16;
    }
}

__global__ void ln_bwd(const float* __restrict__ dyP, int nPart, int pStride,
                       const float* __restrict__ x, const float* __restrict__ s,
                       const float* __restrict__ addend, float* __restrict__ dx,
                       u16* __restrict__ dxb, u16* __restrict__ dxT) {
    __shared__ float sbuf[8];
    __shared__ float xs[D];
    __shared__ float dys[D];
    lnbwd_body(blockIdx.x, dyP, nPart, pStride, x, s, addend, dx, dxb, dxT, xs, dys, sbuf);
}

// ---- merged: W2 update (256 blocks) || dgGEMM split-K (128 blocks) ----
__global__ __launch_bounds__(256) void k_w2upd_dg(
    const u16* __restrict__ uT_, const u16* __restrict__ dhT_,
    float* __restrict__ W2m_, u16* __restrict__ W2n_, u16* __restrict__ W2t_,
    float* __restrict__ b2_,
    const u16* __restrict__ dg_, const u16* __restrict__ W1n_, float* __restrict__ Cp_)
{
    __shared__ __align__(16) u16 S[16384];
    int b = blockIdx.x;
    if (b < 256) {
        upd_body(b & 7, b >> 3, uT_, NTOK, dhT_, NTOK, W2m_, D, NTOK, LR,
                 W2n_, W2t_, HID, b2_, S);
    } else {
        int g = b - 256;   // 0..127 = grid (8,4,4)
        gemm_body(g & 7, (g >> 3) & 3, g >> 5, dg_, HID, W1n_, HID, Cp_, D,
                  512, NTOK * D, nullptr, nullptr, 0, -1, S);
    }
}

// ---- merged: W1 update (256 blocks) || ln2 backward (256 blocks) ----
__global__ __launch_bounds__(256) void k_w1upd_lnbwd(
    const u16* __restrict__ mbT_, const u16* __restrict__ dgT_,
    float* __restrict__ W1m_, u16* __restrict__ W1n_, u16* __restrict__ W1t_,
    float* __restrict__ b1_,
    const float* __restrict__ Cp_, const float* __restrict__ hp_,
    const float* __restrict__ s_, const float* __restrict__ dh_,
    float* __restrict__ dhp_, u16* __restrict__ dhpb_)
{
    __shared__ __align__(16) u16 S[16384];
    int b = blockIdx.x;
    if (b < 256) {
        upd_body(b & 31, b >> 5, mbT_, NTOK, dgT_, NTOK, W1m_, HID, NTOK, LR,
                 W1n_, W1t_, D, b1_, S);
    } else {
        float* xs = (float*)S;
        float* dys = xs + D;
        float* sbuf = dys + D;
        lnbwd_body(b - 256, Cp_, 4, NTOK * D, hp_, s_, dh_, dhp_, dhpb_, nullptr,
                   xs, dys, sbuf);
    }
}

// ---- merged (layer 0): W2 update || W1 update ----
__global__ __launch_bounds__(256) void k_w2w1upd(
    const u16* __restrict__ uT_, const u16* __restrict__ dhT_,
    float* __restrict__ W2m_, u16* __restrict__ W2n_, u16* __restrict__ W2t_,
    float* __restrict__ b2_,
    const u16* __restrict__ mbT_, const u16* __restrict__ dgT_,
    float* __restrict__ W1m_, u16* __restrict__ W1n_, u16* __restrict__ W1t_,
    float* __restrict__ b1_)
{
    __shared__ __align__(16) u16 S[16384];
    int b = blockIdx.x;
    if (b < 256) {
        upd_body(b & 7, b >> 3, uT_, NTOK, dhT_, NTOK, W2m_, D, NTOK, LR,
                 W2n_, W2t_, HID, b2_, S);
    } else {
        int g = b - 256;
        upd_body(g & 31, g >> 5, mbT_, NTOK, dgT_, NTOK, W1m_, HID, NTOK, LR,
                 W1n_, W1t_, D, b1_, S);
    }
}

// ---------------- attention forward (fp32 core, bf16 O) ----------------
__global__ __launch_bounds__(128) void attn_fwd(const float* __restrict__ qkv,
        float* __restrict__ att, u16* __restrict__ O) {
    int bh = blockIdx.x, b = bh >> 3, h = bh & 7;
    __shared__ float Ks[128][64];
    __shared__ float Vs[128][64];
    for (int idx = threadIdx.x; idx < 128 * 64; idx += 128) {
        int j = idx >> 6, d = idx & 63;
        int row = b * 128 + j;
        Ks[j][d] = qkv[(size_t)row * 1536 + 512 + h * 64 + d];
        Vs[j][d] = qkv[(size_t)row * 1536 + 1024 + h * 64 + d];
    }
    __syncthreads();
    int i = threadIdx.x;
    int row = b * 128 + i;
    float q[64];
#pragma unroll
    for (int d = 0; d < 64; d++) q[d] = qkv[(size_t)row * 1536 + h * 64 + d];
    float* arow = att + ((size_t)bh * 128 + i) * 128;
    float mmax = -1e30f, ssum = 0.f;
    for (int j = 0; j <= i; j++) {
        float sc = 0;
#pragma unroll
        for (int d = 0; d < 64; d++) sc += q[d] * Ks[j][d];
        sc *= 0.125f;
        arow[j] = sc;
        float mn = fmaxf(mmax, sc);
        ssum = ssum * expf(mmax - mn) + expf(sc - mn);
        mmax = mn;
    }
    float inv = 1.f / ssum;
    float o[64];
#pragma unroll
    for (int d = 0; d < 64; d++) o[d] = 0.f;
    for (int j = 0; j < 128; j++) {
        float p = (j <= i) ? expf(arow[j] - mmax) * inv : 0.f;
        arow[j] = p;
#pragma unroll
        for (int d = 0; d < 64; d++) o[d] += p * Vs[j][d];
    }
#pragma unroll
    for (int d = 0; d < 64; d++) O[(size_t)row * 512 + h * 64 + d] = f2b(o[d]);
}

// ---------------- attention backward, fused ----------------
__global__ __launch_bounds__(128) void attn_bwd(const float* __restrict__ qkv,
        const float* __restrict__ att, const float* __restrict__ dO,
        float* __restrict__ dS, u16* __restrict__ dqkv) {
    int bh = blockIdx.x, b = bh >> 3, h = bh & 7;
    __shared__ float Ks[128][64];   // phase A: K, phase B: Q
    __shared__ float Vs[128][64];   // phase A: V, phase B: dO
    for (int idx = threadIdx.x; idx < 128 * 64; idx += 128) {
        int j = idx >> 6, d = idx & 63;
        int row = b * 128 + j;
        Ks[j][d] = qkv[(size_t)row * 1536 + 512 + h * 64 + d];
        Vs[j][d] = qkv[(size_t)row * 1536 + 1024 + h * 64 + d];
    }
    __syncthreads();
    {   // ---- phase A: per-row dS + dq ----
        int i = threadIdx.x;
        int row = b * 128 + i;
        float dOi[64];
#pragma unroll
        for (int d = 0; d < 64; d++) dOi[d] = dO[(size_t)row * 512 + h * 64 + d];
        const float* arow = att + ((size_t)bh * 128 + i) * 128;
        float* dsrow = dS + ((size_t)bh * 128 + i) * 128;
        float rowdot = 0.f;
        for (int j = 0; j <= i; j++) {
            float dA = 0;
#pragma unroll
            for (int d = 0; d < 64; d++) dA += dOi[d] * Vs[j][d];
            dsrow[j] = dA;
            rowdot += dA * arow[j];
        }
        float dq[64];
#pragma unroll
        for (int d = 0; d < 64; d++) dq[d] = 0.f;
        for (int j = 0; j <= i; j++) {
            float ds = arow[j] * (dsrow[j] - rowdot);
            dsrow[j] = ds;
#pragma unroll
            for (int d = 0; d < 64; d++) dq[d] += ds * Ks[j][d];
        }
#pragma unroll
        for (int d = 0; d < 64; d++)
            dqkv[(size_t)row * 1536 + h * 64 + d] = f2b(dq[d] * 0.125f);
    }
    __syncthreads();
    // reload: Q -> Ks, dO -> Vs
    for (int idx = threadIdx.x; idx < 128 * 64; idx += 128) {
        int j = idx >> 6, d = idx & 63;
        int row = b * 128 + j;
        Ks[j][d] = qkv[(size_t)row * 1536 + h * 64 + d];
        Vs[j][d] = dO[(size_t)row * 512 + h * 64 + d];
    }
    __syncthreads();
    {   // ---- phase B: per-col dk, dv ----
        int j = threadIdx.x;
        float dk[64], dv[64];
#pragma unroll
        for (int d = 0; d < 64; d++) { dk[d] = 0.f; dv[d] = 0.f; }
        for (int i = j; i < 128; i++) {
            float a_ = att[((size_t)bh * 128 + i) * 128 + j];
            float ds = dS[((size_t)bh * 128 + i) * 128 + j];
#pragma unroll
            for (int d = 0; d < 64; d++) { dv[d] += a_ * Vs[i][d]; dk[d] += ds * Ks[i][d]; }
        }
        int row = b * 128 + j;
#pragma unroll
        for (int d = 0; d < 64; d++) {
            dqkv[(size_t)row * 1536 + 512 + h * 64 + d] = f2b(dk[d] * 0.125f);
            dqkv[(size_t)row * 1536 + 1024 + h * 64 + d] = f2b(dv[d]);
        }
    }
}

// ---------------- cross-entropy gradient: 2 passes, vectorized ----------------
__global__ void ce_grad(const float* __restrict__ outbuf, const int* __restrict__ x,
                        u16* __restrict__ dl, int c) {
    __shared__ float sbuf[8];
    int n = blockIdx.x;
    int b = n >> 7, i = n & 127;
    int tgt = x[b * T + c * MB + i + 1];
    const float* lrow = outbuf + ((size_t)(b * 1024 + c * MB + i)) * V;
    const f32x4* l4 = (const f32x4*)lrow;
    float mx = -1e30f, se = 0.f;
    for (int v = threadIdx.x; v < V / 4; v += blockDim.x) {
        f32x4 q = l4[v];
#pragma unroll
        for (int e = 0; e < 4; e++) {
            float t = q[e];
            if (t > mx) { se = se * expf(mx - t) + 1.f; mx = t; }
            else se += expf(t - mx);
        }
    }
    float M = block_max(mx, sbuf);
    se *= expf(mx - M);
    float S = block_sum(se, sbuf);
    float inv = 1.f / S;
    u16x4* d4 = (u16x4*)(dl + (size_t)n * V);
    for (int v = threadIdx.x; v < V / 4; v += blockDim.x) {
        f32x4 q = l4[v];
        u16x4 o;
#pragma unroll
        for (int e = 0; e < 4; e++) {
            int idx = 4 * v + e;
            float p = expf(q[e] - M) * inv;
            o[e] = f2b((p - (idx == tgt ? 1.f : 0.f)) * (1.f / 256.f));
        }
        d4[v] = o;
    }
}

// ---------------- host orchestration ----------------
extern "C" void kernel_launch(void* const* d_in, const int* in_sizes, int n_in,
                              void* d_out, int out_size, void* d_ws, size_t ws_size,
                              hipStream_t stream) {
    const int* x = (const int*)d_in[0];
    const float* emb = (const float*)d_in[1];
    const float* pos = (const float*)d_in[2];
    const float* ln1_s = (const float*)d_in[3];
    const float* ln1_b = (const float*)d_in[4];
    const float* Wqkv = (const float*)d_in[5];
    const float* bqkv = (const float*)d_in[6];
    const float* Wo = (const float*)d_in[7];
    const float* bo = (const float*)d_in[8];
    const float* ln2_s = (const float*)d_in[9];
    const float* ln2_b = (const float*)d_in[10];
    const float* W1in = (const float*)d_in[11];
    const float* b1in = (const float*)d_in[12];
    const float* W2in = (const float*)d_in[13];
    const float* b2in = (const float*)d_in[14];
    const float* lnf_s = (const float*)d_in[15];
    const float* lnf_b = (const float*)d_in[16];
    const float* Whead = (const float*)d_in[17];
    const float* bhead = (const float*)d_in[18];
    float* out = (float*)d_out;

    float* ws = (float*)d_ws;
    size_t off = 0;
    auto alloc4 = [&](size_t n) { float* p = ws + off; off += (n + 3) & ~(size_t)3; return p; };
    auto allocH = [&](size_t n) { return (u16*)alloc4((n + 1) / 2); };

    // fp32 masters for trained params
    float* W1m = alloc4((size_t)LAYERS * D * HID);
    float* W2m = alloc4((size_t)LAYERS * HID * D);
    float* b1w = alloc4((size_t)LAYERS * HID);
    float* b2w = alloc4((size_t)LAYERS * D);
    // bf16 weight copies (natural + transposed)
    u16* W1n = allocH((size_t)LAYERS * D * HID);
    u16* W1t = allocH((size_t)LAYERS * D * HID);
    u16* W2n = allocH((size_t)LAYERS * HID * D);
    u16* W2t = allocH((size_t)LAYERS * HID * D);
    u16* Wqkv_n = allocH((size_t)LAYERS * D * 3 * D);
    u16* Wqkv_t = allocH((size_t)LAYERS * D * 3 * D);
    u16* Wo_n = allocH((size_t)LAYERS * D * D);
    u16* Wo_t = allocH((size_t)LAYERS * D * D);
    u16* Whead_n = allocH((size_t)D * V);
    u16* Whead_t = allocH((size_t)D * V);
    // activations
    float* h0all = alloc4((size_t)NCHUNK * NTOK * D);
    u16* abf0 = allocH((size_t)NCHUNK * NTOK * D);
    float* h[5];  // h[0] set per-chunk from h0all
    for (int i = 1; i < 5; i++) h[i] = alloc4((size_t)NTOK * D);
    float* hp[4]; for (int i = 0; i < 4; i++) hp[i] = alloc4((size_t)NTOK * D);
    u16* a_bf = allocH((size_t)NTOK * D);
    float* qkvb[4]; for (int i = 0; i < 4; i++) qkvb[i] = alloc4((size_t)NTOK * 3 * D);
    float* attb[4]; for (int i = 0; i < 4; i++) attb[i] = alloc4((size_t)BATCH * NH * MB * MB);
    u16* O_bf = allocH((size_t)NTOK * D);
    u16* mb_bf[4]; for (int i = 0; i < 4; i++) mb_bf[i] = allocH((size_t)NTOK * D);
    u16* mbT[4]; for (int i = 0; i < 4; i++) mbT[i] = allocH((size_t)D * NTOK);
    float* gbuf[4]; for (int i = 0; i < 4; i++) gbuf[i] = alloc4((size_t)NTOK * HID);
    u16* u_bf[4]; for (int i = 0; i < 4; i++) u_bf[i] = allocH((size_t)NTOK * HID);
    u16* uT[4]; for (int i = 0; i < 4; i++) uT[i] = allocH((size_t)HID * NTOK);
    u16* af_bf = allocH((size_t)NTOK * D);
    u16* dlog_bf = allocH((size_t)NTOK * V);
    float* Cpart = alloc4((size_t)SPLITK * NTOK * D);
    float* t512 = alloc4((size_t)NTOK * D);
    float* dh = alloc4((size_t)NTOK * D);
    u16* dh_bf = allocH((size_t)NTOK * D);
    u16* dhT = allocH((size_t)D * NTOK);
    float* dhp = alloc4((size_t)NTOK * D);
    u16* dhp_bf = allocH((size_t)NTOK * D);
    u16* dg_bf = allocH((size_t)NTOK * HID);
    u16* dgT = allocH((size_t)HID * NTOK);
    u16* dqkv_bf = allocH((size_t)NTOK * 3 * D);
    float* dS = alloc4((size_t)BATCH * NH * MB * MB);

    dim3 blk256(256);

    // ---- one-time (per launch) weight conversions ----
    hipMemcpyAsync(W1m, W1in, (size_t)LAYERS * D * HID * 4, hipMemcpyDeviceToDevice, stream);
    hipMemcpyAsync(W2m, W2in, (size_t)LAYERS * HID * D * 4, hipMemcpyDeviceToDevice, stream);
    hipMemcpyAsync(b1w, b1in, (size_t)LAYERS * HID * 4, hipMemcpyDeviceToDevice, stream);
    hipMemcpyAsync(b2w, b2in, (size_t)LAYERS * D * 4, hipMemcpyDeviceToDevice, stream);
    for (int l = 0; l < LAYERS; l++) {
        conv_nt<<<dim3(1536 / 64, 512 / 64), blk256, 0, stream>>>(
            Wqkv + (size_t)l * D * 1536, Wqkv_n + (size_t)l * D * 1536,
            Wqkv_t + (size_t)l * D * 1536, 512, 1536);
        conv_nt<<<dim3(8, 8), blk256, 0, stream>>>(
            Wo + (size_t)l * D * D, Wo_n + (size_t)l * D * D,
            Wo_t + (size_t)l * D * D, 512, 512);
        conv_nt<<<dim3(32, 8), blk256, 0, stream>>>(
            W1in + (size_t)l * D * HID, W1n + (size_t)l * D * HID,
            W1t + (size_t)l * D * HID, 512, 2048);
        conv_nt<<<dim3(8, 32), blk256, 0, stream>>>(
            W2in + (size_t)l * HID * D, W2n + (size_t)l * HID * D,
            W2t + (size_t)l * HID * D, 2048, 512);
    }
    conv_nt<<<dim3(500, 8), blk256, 0, stream>>>(Whead, Whead_n, Whead_t, 512, 32000);
    // all chunks' embedding + layer-0 ln1 (inputs static)
    embed_ln_all<<<dim3(NTOK, NCHUNK), blk256, 0, stream>>>(
        x, emb, pos, ln1_s, ln1_b, h0all, abf0);

    // gemm helper: C = A[MxK] * Bt[NxK]^T
    auto G = [&](const u16* A, int lda, const u16* Bt, int ldb, float* C, int ldc,
                 int M, int N, int K, const float* bias, const float* res, int ldres,
                 int remapc) {
        gemm64<<<dim3(N / 64, M / 64), blk256, 0, stream>>>(
            A, lda, Bt, ldb, C, ldc, K, 0, bias, res, ldres, remapc);
    };

    for (int c = 0; c < NCHUNK; c++) {
        h[0] = h0all + (size_t)c * NTOK * D;
        const u16* a0 = abf0 + (size_t)c * NTOK * D;
        // ================ forward ================
        for (int l = 0; l < LAYERS; l++) {
            const u16* aIn = (l == 0) ? a0 : a_bf;
            G(aIn, D, Wqkv_t + (size_t)l * D * 1536, D, qkvb[l], 1536,
              NTOK, 1536, D, bqkv + l * 1536, nullptr, 0, -1);
            attn_fwd<<<16, 128, 0, stream>>>(qkvb[l], attb[l], O_bf);
            G(O_bf, D, Wo_t + (size_t)l * D * D, D, hp[l], D,
              NTOK, D, D, bo + l * D, h[l], D, -1);
            ln_fwd<<<NTOK, blk256, 0, stream>>>(hp[l], ln2_s + l * D, ln2_b + l * D,
                                                mb_bf[l], mbT[l]);
            gemm64_gelu<<<dim3(HID / 64, NTOK / 64), blk256, 0, stream>>>(
                mb_bf[l], D, W1t + (size_t)l * D * HID, D, D,
                b1w + l * HID, gbuf[l], u_bf[l], uT[l]);
            // FF2 split-K(4) partials
            gemm64<<<dim3(D / 64, NTOK / 64, 4), blk256, 0, stream>>>(
                u_bf[l], HID, W2t + (size_t)l * D * HID, HID, Cpart, D,
                512, NTOK * D, nullptr, nullptr, 0, -1);
            // finalize h[l+1] + LN (next ln1 or final lnf)
            if (l < LAYERS - 1)
                ln_fwd_sum<<<NTOK, blk256, 0, stream>>>(
                    Cpart, 4, hp[l], b2w + l * D, h[l + 1],
                    ln1_s + (l + 1) * D, ln1_b + (l + 1) * D, a_bf);
            else
                ln_fwd_sum<<<NTOK, blk256, 0, stream>>>(
                    Cpart, 4, hp[l], b2w + l * D, h[4], lnf_s, lnf_b, af_bf);
        }
        // head GEMM writes directly into d_out with chunk row remap
        G(af_bf, D, Whead_t, D, out, V, NTOK, V, D, bhead, nullptr, 0, c);

        // ================ backward ================
        ce_grad<<<NTOK, blk256, 0, stream>>>(out, x, dlog_bf, c);
        gemm64<<<dim3(D / 64, NTOK / 64, SPLITK), blk256, 0, stream>>>(
            dlog_bf, V, Whead_n, V, Cpart, D, SKLEN, NTOK * D,
            nullptr, nullptr, 0, -1);
        ln_bwd<<<NTOK, blk256, 0, stream>>>(Cpart, SPLITK, NTOK * D, h[4], lnf_s,
                                            nullptr, dh, dh_bf, dhT);
        for (int l = LAYERS - 1; l >= 1; l--) {
            gemm64_dgelu<<<dim3(HID / 64, NTOK / 64), blk256, 0, stream>>>(
                dh_bf, D, W2n + (size_t)l * HID * D, D, D, gbuf[l], dg_bf, dgT);
            // W2 update (uses old W2t? no: W2t refreshed here, W2n read was in dgelu)
            k_w2upd_dg<<<384, blk256, 0, stream>>>(
                uT[l], dhT, W2m + (size_t)l * HID * D,
                W2n + (size_t)l * HID * D, W2t + (size_t)l * HID * D, b2w + l * D,
                dg_bf, W1n + (size_t)l * D * HID, Cpart);
            k_w1upd_lnbwd<<<512, blk256, 0, stream>>>(
                mbT[l], dgT, W1m + (size_t)l * D * HID,
                W1n + (size_t)l * D * HID, W1t + (size_t)l * D * HID, b1w + l * HID,
                Cpart, hp[l], ln2_s + l * D, dh, dhp, dhp_bf);
            G(dhp_bf, D, Wo_n + (size_t)l * D * D, D, t512, D,
              NTOK, D, D, nullptr, nullptr, 0, -1);
            attn_bwd<<<16, 128, 0, stream>>>(qkvb[l], attb[l], t512, dS, dqkv_bf);
            gemm64<<<dim3(D / 64, NTOK / 64, 3), blk256, 0, stream>>>(
                dqkv_bf, 1536, Wqkv_n + (size_t)l * D * 1536, 1536, Cpart, D,
                512, NTOK * D, nullptr, nullptr, 0, -1);
            ln_bwd<<<NTOK, blk256, 0, stream>>>(Cpart, 3, NTOK * D, h[l],
                                                ln1_s + l * D, dhp, dh, dh_bf, dhT);
        }
        // ---- layer 0: only MLP weight grads are live ----
        gemm64_dgelu<<<dim3(HID / 64, NTOK / 64), blk256, 0, stream>>>(
            dh_bf, D, W2n, D, D, gbuf[0], dg_bf, dgT);
        k_w2w1upd<<<512, blk256, 0, stream>>>(
            uT[0], dhT, W2m, W2n, W2t, b2w,
            mbT[0], dgT, W1m, W1n, W1t, b1w);
    }
}